// Round 3
// baseline (20078.732 us; speedup 1.0000x reference)
//
#include <hip/hip_runtime.h>
#include <hip/hip_fp16.h>

// ---------------------------------------------------------------------------
// NeuralODE RK4, PERSISTENT kernel: each block owns 128 rows and integrates
// all 40 steps x 4 stages on-chip (y, acc, k in registers; activations via
// LDS hi/lo bf16 tile). Eliminates all inter-stage HBM traffic.
//
// f(y) = tanh(relu(relu(y W1+b1) W2'+b2') Wo'+bo')   (BN folded into W2',Wo')
// GEMM precision: bf16 hi/lo split as one K=768 contraction:
//   A' cols [0,256)=Ah [256,512)=Al [512,768)=Ah ; B' rows [Bh|Bh|Bl]
// RK4 accumulator stored as packed fp16 pairs (register relief; |acc|<=dt).
// ---------------------------------------------------------------------------

typedef unsigned short u16;
typedef unsigned int   u32;
typedef __attribute__((ext_vector_type(8))) short bf16x8;
typedef __attribute__((ext_vector_type(4))) float f32x4;

#define BN_EPS 1e-3f
#define NROWS  65536
#define BM     128
#define NTHR   512
#define WT_ELEMS 196608     // 768*256 per layer

__device__ __forceinline__ u16 f2bf(float f) {         // RNE f32 -> bf16 bits
    u32 u = __float_as_uint(f);
    u32 r = u + 0x7FFFu + ((u >> 16) & 1u);
    return (u16)(r >> 16);
}
__device__ __forceinline__ float bf2f(u16 h) {
    return __uint_as_float(((u32)h) << 16);
}
__device__ __forceinline__ float fast_tanh(float x) {
    float e = __expf(2.0f * x);
    return 1.0f - __fdividef(2.0f, e + 1.0f);
}
__device__ __forceinline__ u32 pack_h2(float a, float b) {
    __half2 h = __floats2half2_rn(a, b);
    return *reinterpret_cast<u32*>(&h);
}
__device__ __forceinline__ float2 unpack_h2(u32 v) {
    __half2 h = *reinterpret_cast<__half2*>(&v);
    return __half22float2(h);
}

// LDS act tile [128 rows][512 bf16] (row = [Ah 512B | Al 512B], stride 1KiB).
// XOR swizzle breaks the 16-way bank conflict of the stride-1KiB column read.
#define SWZ(row, kb) (((row) << 10) + ((kb) ^ (((row) & 7) << 4)))

// ---------------------------------------------------------------------------
__global__ void prep_bias(const float* __restrict__ b2,
                          const float* __restrict__ g1, const float* __restrict__ be1,
                          const float* __restrict__ m1, const float* __restrict__ v1,
                          const float* __restrict__ W2,
                          const float* __restrict__ bo,
                          const float* __restrict__ g2, const float* __restrict__ be2,
                          const float* __restrict__ m2, const float* __restrict__ v2,
                          const float* __restrict__ Wo,
                          float* __restrict__ b2o, float* __restrict__ boo) {
    int t = threadIdx.x;
    if (t < 256) {
        float s = b2[t];
        for (int i = 0; i < 256; ++i) {
            float s1 = g1[i] * rsqrtf(v1[i] + BN_EPS);
            float t1 = be1[i] - s1 * m1[i];
            s += t1 * W2[i * 256 + t];
        }
        b2o[t] = s;
    } else {
        int j = t - 256;
        float s = bo[j];
        for (int i = 0; i < 256; ++i) {
            float s2 = g2[i] * rsqrtf(v2[i] + BN_EPS);
            float t2 = be2[i] - s2 * m2[i];
            s += t2 * Wo[i * 256 + j];
        }
        boo[j] = s;
    }
}

// scale + split + frag-linear-swizzle weights (1KiB coalesced B-frag loads)
__global__ void prep_weights(const float* __restrict__ W1, const float* __restrict__ W2,
                             const float* __restrict__ Wo,
                             const float* __restrict__ g1, const float* __restrict__ v1,
                             const float* __restrict__ g2, const float* __restrict__ v2,
                             u16* __restrict__ Wt) {
    int tid = blockIdx.x * 256 + threadIdx.x;
    if (tid >= 3 * 768 * 256) return;
    int l   = tid / (768 * 256);
    int r   = tid % (768 * 256);
    int kp  = r >> 8;
    int col = r & 255;
    int ok  = kp & 255;
    float w;
    if (l == 0)      w = W1[ok * 256 + col];
    else if (l == 1) w = W2[ok * 256 + col] * (g1[ok] * rsqrtf(v1[ok] + BN_EPS));
    else             w = Wo[ok * 256 + col] * (g2[ok] * rsqrtf(v2[ok] + BN_EPS));
    u16 hi = f2bf(w);
    u16 out = (kp < 512) ? hi : f2bf(w - bf2f(hi));   // [Bh|Bh|Bl]
    int ks = kp >> 5, gg = (kp >> 3) & 3, j = kp & 7, cb = col >> 4, cc = col & 15;
    Wt[(size_t)l * WT_ELEMS + ks * 8192 + cb * 512 + cc * 32 + gg * 8 + j] = out;
}

// ---------------------------------------------------------------------------
__global__ __launch_bounds__(NTHR, 2)
void ode_persistent(const float* __restrict__ y0, float* __restrict__ yout,
                    const u16* __restrict__ Wt,
                    const float* __restrict__ b1, const float* __restrict__ b2o,
                    const float* __restrict__ boo) {
    extern __shared__ char smem[];
    const int t = threadIdx.x;
    const size_t rowbase = (size_t)blockIdx.x * BM;
    const int lane = t & 63, wid = t >> 6;
    const int wr = wid >> 2, wc = wid & 3;     // 2 (row) x 4 (col) waves
    const int c16 = lane & 15, g = lane >> 4;

    // per-thread state in MFMA C-layout: row=wr*64+m*16+g*4+j, col=wc*64+n*16+c16
    f32x4 Y[4][4];          // y (f32)
    f32x4 K[4][4];          // shared: GEMM accumulator / current k
    u32   A2[4][4][2];      // RK4 accumulator, packed fp16 pairs (j01, j23)

#pragma unroll
    for (int m = 0; m < 4; ++m)
#pragma unroll
        for (int n = 0; n < 4; ++n) {
            const int col = wc * 64 + n * 16 + c16;
#pragma unroll
            for (int j = 0; j < 4; ++j) {
                const int row = wr * 64 + m * 16 + g * 4 + j;
                Y[m][n][j] = y0[(rowbase + row) * 256 + col];
            }
            K[m][n] = (f32x4){0.f, 0.f, 0.f, 0.f};   // k_prev=0 for stage 0 (c=0)
            A2[m][n][0] = 0u; A2[m][n][1] = 0u;
        }

    const float dt  = 1.0f / 40.0f;
    const float c2  = 0.5f * dt;
    const float w16 = dt / 6.0f, w13 = dt / 3.0f;

    for (int it = 0; it < 160; ++it) {
        const int stage = it & 3;
        const float c = (stage == 0) ? 0.0f : ((stage == 3) ? dt : c2);
        const float w = (stage == 1 || stage == 2) ? w13 : w16;

        // ---- prologue: x = Y + c*K ; trunc-hi / RNE-lo split into LDS ----
#pragma unroll
        for (int m = 0; m < 4; ++m)
#pragma unroll
            for (int n = 0; n < 4; ++n) {
                const int col2 = (wc * 64 + n * 16 + c16) * 2;
#pragma unroll
                for (int j = 0; j < 4; ++j) {
                    const int row = wr * 64 + m * 16 + g * 4 + j;
                    const float x = fmaf(c, K[m][n][j], Y[m][n][j]);
                    const u32 xb = __float_as_uint(x);
                    const u16 hi = (u16)(xb >> 16);
                    const float fl = x - __uint_as_float(xb & 0xFFFF0000u);
                    *reinterpret_cast<u16*>(smem + SWZ(row, col2))       = hi;
                    *reinterpret_cast<u16*>(smem + SWZ(row, 512 + col2)) = f2bf(fl);
                }
            }
        __syncthreads();

        // ---- 3 layers (rolled: keep the 160-iter body inside the I-cache) ----
#pragma unroll 1
        for (int l = 0; l < 3; ++l) {
            const u16* __restrict__ wt = Wt + (size_t)l * WT_ELEMS;
            const float* bp = (l == 0) ? b1 : ((l == 1) ? b2o : boo);

#pragma unroll
            for (int n = 0; n < 4; ++n) {
                const float bv = bp[wc * 64 + n * 16 + c16];
                const f32x4 b4 = {bv, bv, bv, bv};
#pragma unroll
                for (int m = 0; m < 4; ++m) K[m][n] = b4;
            }

#pragma unroll 2
            for (int ks = 0; ks < 24; ++ks) {
                const int kfull = ks * 32;
                const int kloc  = (kfull >= 512) ? (kfull - 512) : kfull;
                const int kb    = kloc * 2 + g * 16;
                bf16x8 av[4], bv[4];
#pragma unroll
                for (int m = 0; m < 4; ++m) {
                    const int row = wr * 64 + m * 16 + c16;
                    av[m] = *reinterpret_cast<const bf16x8*>(smem + SWZ(row, kb));
                }
                const u16* wp = wt + (size_t)(ks * 16 + wc * 4) * 512 + c16 * 32 + g * 8;
#pragma unroll
                for (int n = 0; n < 4; ++n)
                    bv[n] = *reinterpret_cast<const bf16x8*>(wp + n * 512);
#pragma unroll
                for (int m = 0; m < 4; ++m)
#pragma unroll
                    for (int n = 0; n < 4; ++n)
                        K[m][n] = __builtin_amdgcn_mfma_f32_16x16x32_bf16(
                            av[m], bv[n], K[m][n], 0, 0, 0);
            }
            __syncthreads();   // act reads done before overwrite / next prologue

            if (l < 2) {
                // relu -> hi/lo split -> same LDS tile
#pragma unroll
                for (int m = 0; m < 4; ++m)
#pragma unroll
                    for (int n = 0; n < 4; ++n) {
                        const int col2 = (wc * 64 + n * 16 + c16) * 2;
#pragma unroll
                        for (int j = 0; j < 4; ++j) {
                            const int row = wr * 64 + m * 16 + g * 4 + j;
                            const float h = fmaxf(K[m][n][j], 0.0f);
                            const u32 hb = __float_as_uint(h);
                            const u16 hi = (u16)(hb >> 16);
                            const float fl = h - __uint_as_float(hb & 0xFFFF0000u);
                            *reinterpret_cast<u16*>(smem + SWZ(row, col2))       = hi;
                            *reinterpret_cast<u16*>(smem + SWZ(row, 512 + col2)) = f2bf(fl);
                        }
                    }
                __syncthreads();
            }
        }

        // ---- epilogue: k = tanh(out); RK4 bookkeeping (registers only) ----
        if (stage < 3) {
#pragma unroll
            for (int m = 0; m < 4; ++m)
#pragma unroll
                for (int n = 0; n < 4; ++n) {
                    f32x4 kv;
#pragma unroll
                    for (int j = 0; j < 4; ++j) kv[j] = fast_tanh(K[m][n][j]);
                    K[m][n] = kv;                       // k for next prologue
                    float2 p0 = unpack_h2(A2[m][n][0]);
                    float2 p1 = unpack_h2(A2[m][n][1]);
                    A2[m][n][0] = pack_h2(fmaf(w, kv[0], p0.x), fmaf(w, kv[1], p0.y));
                    A2[m][n][1] = pack_h2(fmaf(w, kv[2], p1.x), fmaf(w, kv[3], p1.y));
                }
        } else {
            // y += acc + w*k4 ; reset acc (K not needed next prologue: c=0)
#pragma unroll
            for (int m = 0; m < 4; ++m)
#pragma unroll
                for (int n = 0; n < 4; ++n) {
                    float2 p0 = unpack_h2(A2[m][n][0]);
                    float2 p1 = unpack_h2(A2[m][n][1]);
                    f32x4 yv = Y[m][n];
                    yv[0] += p0.x + w * fast_tanh(K[m][n][0]);
                    yv[1] += p0.y + w * fast_tanh(K[m][n][1]);
                    yv[2] += p1.x + w * fast_tanh(K[m][n][2]);
                    yv[3] += p1.y + w * fast_tanh(K[m][n][3]);
                    Y[m][n] = yv;
                    A2[m][n][0] = 0u; A2[m][n][1] = 0u;
                }
        }
    }

    // ---- final store ----
#pragma unroll
    for (int m = 0; m < 4; ++m)
#pragma unroll
        for (int n = 0; n < 4; ++n) {
            const int col = wc * 64 + n * 16 + c16;
#pragma unroll
            for (int j = 0; j < 4; ++j) {
                const int row = wr * 64 + m * 16 + g * 4 + j;
                yout[(rowbase + row) * 256 + col] = Y[m][n][j];
            }
        }
}

// ---------------------------------------------------------------------------
extern "C" void kernel_launch(void* const* d_in, const int* in_sizes, int n_in,
                              void* d_out, int out_size, void* d_ws, size_t ws_size,
                              hipStream_t stream) {
    const float* y0  = (const float*)d_in[0];
    const float* W1  = (const float*)d_in[1];
    const float* b1  = (const float*)d_in[2];
    const float* g1  = (const float*)d_in[3];
    const float* be1 = (const float*)d_in[4];
    const float* m1  = (const float*)d_in[5];
    const float* v1  = (const float*)d_in[6];
    const float* W2  = (const float*)d_in[7];
    const float* b2  = (const float*)d_in[8];
    const float* g2  = (const float*)d_in[9];
    const float* be2 = (const float*)d_in[10];
    const float* m2  = (const float*)d_in[11];
    const float* v2  = (const float*)d_in[12];
    const float* Wo  = (const float*)d_in[13];
    const float* bo  = (const float*)d_in[14];

    float* y = (float*)d_out;
    char*  ws = (char*)d_ws;
    const size_t MB = 1024 * 1024;
    u16*   Wt   = (u16*)(ws);                 // 1.125 MiB
    float* b2o  = (float*)(ws + 2 * MB);
    float* boo  = b2o + 256;

    hipFuncSetAttribute(reinterpret_cast<const void*>(&ode_persistent),
                        hipFuncAttributeMaxDynamicSharedMemorySize, 131072);

    prep_bias<<<1, 512, 0, stream>>>(b2, g1, be1, m1, v1, W2,
                                     bo, g2, be2, m2, v2, Wo, b2o, boo);
    prep_weights<<<2304, 256, 0, stream>>>(W1, W2, Wo, g1, v1, g2, v2, Wt);

    ode_persistent<<<NROWS / BM, NTHR, 131072, stream>>>(y0, y, Wt, b1, b2o, boo);
}

// Round 5
// 17777.145 us; speedup vs baseline: 1.1295x; 1.1295x over previous
//
#include <hip/hip_runtime.h>
#include <hip/hip_fp16.h>

// ---------------------------------------------------------------------------
// NeuralODE RK4, PERSISTENT kernel v2 (anti-spill).
// Round-3 post-mortem: 28 GB of HBM traffic was register scratch spill
// (compiler capped arch VGPRs at 128, state needs ~160). Fixes:
//   - amdgpu_waves_per_eu(2,2): occupancy IS 2 waves/SIMD (128 KiB LDS,
//     1 block/CU), so give each wave the full 256-reg budget.
//   - k packed as bf16 pairs between stages (32 u32, dead during GEMMs).
//   - RK4 accumulator packed fp16 pairs (|acc| <= dt).
//   - biases staged in LDS (no global loads after per-layer barriers).
//
// f(y) = tanh(relu(relu(y W1+b1) W2'+b2') Wo'+bo')   (BN folded into W2',Wo')
// GEMM precision: bf16 hi/lo split as one K=768 contraction:
//   A' cols [0,256)=Ah [256,512)=Al [512,768)=Ah ; B' rows [Bh|Bh|Bl]
// ---------------------------------------------------------------------------

typedef unsigned short u16;
typedef unsigned int   u32;
typedef __attribute__((ext_vector_type(8))) short bf16x8;
typedef __attribute__((ext_vector_type(4))) float f32x4;

#define BN_EPS 1e-3f
#define NROWS  65536
#define BM     128
#define NTHR   512
#define WT_ELEMS 196608       // 768*256 per layer
#define LDS_BIAS 131072       // byte offset of bias region in dynamic LDS
#define LDS_SIZE (131072 + 3072)

__device__ __forceinline__ u16 f2bf(float f) {         // RNE f32 -> bf16 bits
    u32 u = __float_as_uint(f);
    u32 r = u + 0x7FFFu + ((u >> 16) & 1u);
    return (u16)(r >> 16);
}
__device__ __forceinline__ float bf2f(u16 h) {
    return __uint_as_float(((u32)h) << 16);
}
__device__ __forceinline__ float fast_tanh(float x) {
    float e = __expf(2.0f * x);
    return 1.0f - __fdividef(2.0f, e + 1.0f);
}
__device__ __forceinline__ u32 pack_h2(float a, float b) {
    __half2 h = __floats2half2_rn(a, b);
    return *reinterpret_cast<u32*>(&h);
}
__device__ __forceinline__ float2 unpack_h2(u32 v) {
    __half2 h = *reinterpret_cast<__half2*>(&v);
    return __half22float2(h);
}
__device__ __forceinline__ u32 pack_bf2(float a, float b) {   // a->lo16, b->hi16
    return ((u32)f2bf(b) << 16) | (u32)f2bf(a);
}
__device__ __forceinline__ float2 unpack_bf2(u32 p) {
    return make_float2(__uint_as_float(p << 16),
                       __uint_as_float(p & 0xFFFF0000u));
}

// LDS act tile [128 rows][512 bf16] (row = [Ah 512B | Al 512B], stride 1KiB).
// XOR swizzle breaks the 16-way bank conflict of the stride-1KiB column read.
#define SWZ(row, kb) (((row) << 10) + ((kb) ^ (((row) & 7) << 4)))

// ---------------------------------------------------------------------------
__global__ void prep_bias(const float* __restrict__ b2,
                          const float* __restrict__ g1, const float* __restrict__ be1,
                          const float* __restrict__ m1, const float* __restrict__ v1,
                          const float* __restrict__ W2,
                          const float* __restrict__ bo,
                          const float* __restrict__ g2, const float* __restrict__ be2,
                          const float* __restrict__ m2, const float* __restrict__ v2,
                          const float* __restrict__ Wo,
                          float* __restrict__ b2o, float* __restrict__ boo) {
    int t = threadIdx.x;
    if (t < 256) {
        float s = b2[t];
        for (int i = 0; i < 256; ++i) {
            float s1 = g1[i] * rsqrtf(v1[i] + BN_EPS);
            float t1 = be1[i] - s1 * m1[i];
            s += t1 * W2[i * 256 + t];
        }
        b2o[t] = s;
    } else {
        int j = t - 256;
        float s = bo[j];
        for (int i = 0; i < 256; ++i) {
            float s2 = g2[i] * rsqrtf(v2[i] + BN_EPS);
            float t2 = be2[i] - s2 * m2[i];
            s += t2 * Wo[i * 256 + j];
        }
        boo[j] = s;
    }
}

// scale + split + frag-linear-swizzle weights (1KiB coalesced B-frag loads)
__global__ void prep_weights(const float* __restrict__ W1, const float* __restrict__ W2,
                             const float* __restrict__ Wo,
                             const float* __restrict__ g1, const float* __restrict__ v1,
                             const float* __restrict__ g2, const float* __restrict__ v2,
                             u16* __restrict__ Wt) {
    int tid = blockIdx.x * 256 + threadIdx.x;
    if (tid >= 3 * 768 * 256) return;
    int l   = tid / (768 * 256);
    int r   = tid % (768 * 256);
    int kp  = r >> 8;
    int col = r & 255;
    int ok  = kp & 255;
    float w;
    if (l == 0)      w = W1[ok * 256 + col];
    else if (l == 1) w = W2[ok * 256 + col] * (g1[ok] * rsqrtf(v1[ok] + BN_EPS));
    else             w = Wo[ok * 256 + col] * (g2[ok] * rsqrtf(v2[ok] + BN_EPS));
    u16 hi = f2bf(w);
    u16 out = (kp < 512) ? hi : f2bf(w - bf2f(hi));   // [Bh|Bh|Bl]
    int ks = kp >> 5, gg = (kp >> 3) & 3, j = kp & 7, cb = col >> 4, cc = col & 15;
    Wt[(size_t)l * WT_ELEMS + ks * 8192 + cb * 512 + cc * 32 + gg * 8 + j] = out;
}

// ---------------------------------------------------------------------------
__global__ __launch_bounds__(NTHR)
__attribute__((amdgpu_waves_per_eu(2, 2)))
void ode_persistent(const float* __restrict__ y0, float* __restrict__ yout,
                    const u16* __restrict__ Wt,
                    const float* __restrict__ b1, const float* __restrict__ b2o,
                    const float* __restrict__ boo) {
    extern __shared__ char smem[];
    float* bias_lds = reinterpret_cast<float*>(smem + LDS_BIAS);
    const int t = threadIdx.x;
    const size_t rowbase = (size_t)blockIdx.x * BM;
    const int lane = t & 63, wid = t >> 6;
    const int wr = wid >> 2, wc = wid & 3;     // 2 (row) x 4 (col) waves
    const int c16 = lane & 15, g = lane >> 4;

    // stage biases into LDS (3 x 256 f32)
    for (int i = t; i < 768; i += NTHR) {
        float v = (i < 256) ? b1[i] : ((i < 512) ? b2o[i - 256] : boo[i - 512]);
        bias_lds[i] = v;
    }

    // per-thread state in MFMA C-layout: row=wr*64+m*16+g*4+j, col=wc*64+n*16+c16
    f32x4 Y[4][4];          // y, f32 (64 regs; master state)
    u32   Kp[4][4][2];      // k_{s-1}, packed bf16 pairs (dead during GEMMs)
    u32   A2[4][4][2];      // RK4 accumulator, packed fp16 pairs (|acc|<=dt)

#pragma unroll
    for (int m = 0; m < 4; ++m)
#pragma unroll
        for (int n = 0; n < 4; ++n) {
            const int col = wc * 64 + n * 16 + c16;
#pragma unroll
            for (int j = 0; j < 4; ++j) {
                const int row = wr * 64 + m * 16 + g * 4 + j;
                Y[m][n][j] = y0[(rowbase + row) * 256 + col];
            }
            Kp[m][n][0] = 0u; Kp[m][n][1] = 0u;   // k=0 for stage 0 (c=0)
            A2[m][n][0] = 0u; A2[m][n][1] = 0u;
        }
    __syncthreads();   // bias_lds ready

    const float dt  = 1.0f / 40.0f;
    const float c2  = 0.5f * dt;
    const float w16 = dt / 6.0f, w13 = dt / 3.0f;

    for (int it = 0; it < 160; ++it) {
        const int stage = it & 3;
        const float c = (stage == 0) ? 0.0f : ((stage == 3) ? dt : c2);
        const float w = (stage == 1 || stage == 2) ? w13 : w16;

        // ---- prologue: x = Y + c*k_prev ; trunc-hi / RNE-lo split into LDS ----
#pragma unroll
        for (int m = 0; m < 4; ++m)
#pragma unroll
            for (int n = 0; n < 4; ++n) {
                const int col2 = (wc * 64 + n * 16 + c16) * 2;
                const float2 k01 = unpack_bf2(Kp[m][n][0]);
                const float2 k23 = unpack_bf2(Kp[m][n][1]);
                const float kj[4] = {k01.x, k01.y, k23.x, k23.y};
#pragma unroll
                for (int j = 0; j < 4; ++j) {
                    const int row = wr * 64 + m * 16 + g * 4 + j;
                    const float x = fmaf(c, kj[j], Y[m][n][j]);
                    const u32 xb = __float_as_uint(x);
                    const u16 hi = (u16)(xb >> 16);
                    const float fl = x - __uint_as_float(xb & 0xFFFF0000u);
                    *reinterpret_cast<u16*>(smem + SWZ(row, col2))       = hi;
                    *reinterpret_cast<u16*>(smem + SWZ(row, 512 + col2)) = f2bf(fl);
                }
            }
        __syncthreads();

        f32x4 ACC[4][4];   // MFMA accumulator (AGPR-resident)

        // ---- 3 layers (rolled: keep the 160-iter body inside the I-cache) ----
#pragma unroll 1
        for (int l = 0; l < 3; ++l) {
            const u16* __restrict__ wt = Wt + (size_t)l * WT_ELEMS;

            // acc init = bias (per output column), from LDS
#pragma unroll
            for (int n = 0; n < 4; ++n) {
                const float bv = bias_lds[l * 256 + wc * 64 + n * 16 + c16];
                const f32x4 b4 = {bv, bv, bv, bv};
#pragma unroll
                for (int m = 0; m < 4; ++m) ACC[m][n] = b4;
            }

            // K loop over 768 = [Ah|Al|Ah] x [Bh|Bh|Bl]
#pragma unroll 2
            for (int ks = 0; ks < 24; ++ks) {
                const int kfull = ks * 32;
                const int kloc  = (kfull >= 512) ? (kfull - 512) : kfull;
                const int kb    = kloc * 2 + g * 16;
                bf16x8 av[4], bv[4];
#pragma unroll
                for (int m = 0; m < 4; ++m) {
                    const int row = wr * 64 + m * 16 + c16;
                    av[m] = *reinterpret_cast<const bf16x8*>(smem + SWZ(row, kb));
                }
                const u16* wp = wt + (size_t)(ks * 16 + wc * 4) * 512 + c16 * 32 + g * 8;
#pragma unroll
                for (int n = 0; n < 4; ++n)
                    bv[n] = *reinterpret_cast<const bf16x8*>(wp + n * 512);
#pragma unroll
                for (int m = 0; m < 4; ++m)
#pragma unroll
                    for (int n = 0; n < 4; ++n)
                        ACC[m][n] = __builtin_amdgcn_mfma_f32_16x16x32_bf16(
                            av[m], bv[n], ACC[m][n], 0, 0, 0);
            }
            __syncthreads();   // act reads done before overwrite / next prologue

            if (l < 2) {
                // relu -> hi/lo split -> same LDS tile
#pragma unroll
                for (int m = 0; m < 4; ++m)
#pragma unroll
                    for (int n = 0; n < 4; ++n) {
                        const int col2 = (wc * 64 + n * 16 + c16) * 2;
#pragma unroll
                        for (int j = 0; j < 4; ++j) {
                            const int row = wr * 64 + m * 16 + g * 4 + j;
                            const float h = fmaxf(ACC[m][n][j], 0.0f);
                            const u32 hb = __float_as_uint(h);
                            const u16 hi = (u16)(hb >> 16);
                            const float fl = h - __uint_as_float(hb & 0xFFFF0000u);
                            *reinterpret_cast<u16*>(smem + SWZ(row, col2))       = hi;
                            *reinterpret_cast<u16*>(smem + SWZ(row, 512 + col2)) = f2bf(fl);
                        }
                    }
                __syncthreads();
            }
        }

        // ---- epilogue: k = tanh(out); RK4 bookkeeping (registers only) ----
        if (stage < 3) {
#pragma unroll
            for (int m = 0; m < 4; ++m)
#pragma unroll
                for (int n = 0; n < 4; ++n) {
                    const float t0 = fast_tanh(ACC[m][n][0]);
                    const float t1 = fast_tanh(ACC[m][n][1]);
                    const float t2 = fast_tanh(ACC[m][n][2]);
                    const float t3 = fast_tanh(ACC[m][n][3]);
                    Kp[m][n][0] = pack_bf2(t0, t1);
                    Kp[m][n][1] = pack_bf2(t2, t3);
                    const float2 p0 = unpack_h2(A2[m][n][0]);
                    const float2 p1 = unpack_h2(A2[m][n][1]);
                    A2[m][n][0] = pack_h2(fmaf(w, t0, p0.x), fmaf(w, t1, p0.y));
                    A2[m][n][1] = pack_h2(fmaf(w, t2, p1.x), fmaf(w, t3, p1.y));
                }
        } else {
            // y += acc + w*k4 ; reset acc (k not needed next prologue: c=0)
#pragma unroll
            for (int m = 0; m < 4; ++m)
#pragma unroll
                for (int n = 0; n < 4; ++n) {
                    const float2 p0 = unpack_h2(A2[m][n][0]);
                    const float2 p1 = unpack_h2(A2[m][n][1]);
                    f32x4 yv = Y[m][n];
                    yv[0] += p0.x + w * fast_tanh(ACC[m][n][0]);
                    yv[1] += p0.y + w * fast_tanh(ACC[m][n][1]);
                    yv[2] += p1.x + w * fast_tanh(ACC[m][n][2]);
                    yv[3] += p1.y + w * fast_tanh(ACC[m][n][3]);
                    Y[m][n] = yv;
                    A2[m][n][0] = 0u; A2[m][n][1] = 0u;
                }
        }
    }

    // ---- final store ----
#pragma unroll
    for (int m = 0; m < 4; ++m)
#pragma unroll
        for (int n = 0; n < 4; ++n) {
            const int col = wc * 64 + n * 16 + c16;
#pragma unroll
            for (int j = 0; j < 4; ++j) {
                const int row = wr * 64 + m * 16 + g * 4 + j;
                yout[(rowbase + row) * 256 + col] = Y[m][n][j];
            }
        }
}

// ---------------------------------------------------------------------------
extern "C" void kernel_launch(void* const* d_in, const int* in_sizes, int n_in,
                              void* d_out, int out_size, void* d_ws, size_t ws_size,
                              hipStream_t stream) {
    const float* y0  = (const float*)d_in[0];
    const float* W1  = (const float*)d_in[1];
    const float* b1  = (const float*)d_in[2];
    const float* g1  = (const float*)d_in[3];
    const float* be1 = (const float*)d_in[4];
    const float* m1  = (const float*)d_in[5];
    const float* v1  = (const float*)d_in[6];
    const float* W2  = (const float*)d_in[7];
    const float* b2  = (const float*)d_in[8];
    const float* g2  = (const float*)d_in[9];
    const float* be2 = (const float*)d_in[10];
    const float* m2  = (const float*)d_in[11];
    const float* v2  = (const float*)d_in[12];
    const float* Wo  = (const float*)d_in[13];
    const float* bo  = (const float*)d_in[14];

    float* y = (float*)d_out;
    char*  ws = (char*)d_ws;
    const size_t MB = 1024 * 1024;
    u16*   Wt   = (u16*)(ws);                 // 1.125 MiB
    float* b2o  = (float*)(ws + 2 * MB);
    float* boo  = b2o + 256;

    hipFuncSetAttribute(reinterpret_cast<const void*>(&ode_persistent),
                        hipFuncAttributeMaxDynamicSharedMemorySize, LDS_SIZE);

    prep_bias<<<1, 512, 0, stream>>>(b2, g1, be1, m1, v1, W2,
                                     bo, g2, be2, m2, v2, Wo, b2o, boo);
    prep_weights<<<2304, 256, 0, stream>>>(W1, W2, Wo, g1, v1, g2, v2, Wt);

    ode_persistent<<<NROWS / BM, NTHR, LDS_SIZE, stream>>>(y0, y, Wt, b1, b2o, boo);
}